// Round 1
// baseline (1867.545 us; speedup 1.0000x reference)
//
#include <hip/hip_runtime.h>
#include <math.h>

#define GCOUNT 512
#define HDIM 128
#define EPG 2048                 // edges per graph
#define E_TOTAL (GCOUNT * EPG)   // 1,048,576

// ---------------------------------------------------------------- edge init
__global__ __launch_bounds__(256) void k_edge_init(const int* __restrict__ ei,
                                                   int* __restrict__ src,
                                                   int* __restrict__ dst,
                                                   float* __restrict__ we) {
  int e = blockIdx.x * 256 + threadIdx.x;
  src[e] = ei[e];
  dst[e] = ei[E_TOTAL + e];
  we[e] = 1.0f;
}

// ---------------------------------------------------------------- GEMM: C[M,128] = A[M,128] @ W[128,128], f32
// block: 256 threads, tile 64 rows x 128 cols, thread tile 4x8, K chunked by 32.
__global__ __launch_bounds__(256) void k_gemm(const float* __restrict__ A,
                                              const float* __restrict__ W,
                                              float* __restrict__ C) {
  __shared__ float xT[32][68];    // [kk][row], padded for b128 alignment
  __shared__ float wl[32][132];   // [kk][col]
  int t = threadIdx.x;
  size_t row0 = (size_t)blockIdx.x * 64;
  int r0 = (t >> 4) << 2;         // 0..60
  int c0 = (t & 15) << 3;         // 0..120
  float acc[4][8];
#pragma unroll
  for (int i = 0; i < 4; i++)
#pragma unroll
    for (int j = 0; j < 8; j++) acc[i][j] = 0.f;

  for (int k0 = 0; k0 < 128; k0 += 32) {
#pragma unroll
    for (int i = 0; i < 2; i++) {           // 64 rows x 32 k as float4, transposed store
      int f = t + i * 256;
      int r = f >> 3;
      int kk4 = (f & 7) << 2;
      float4 v = *(const float4*)&A[(row0 + r) * HDIM + k0 + kk4];
      xT[kk4 + 0][r] = v.x; xT[kk4 + 1][r] = v.y;
      xT[kk4 + 2][r] = v.z; xT[kk4 + 3][r] = v.w;
    }
#pragma unroll
    for (int i = 0; i < 4; i++) {           // 32 k x 128 cols
      int f = t + i * 256;
      int kk = f >> 5;
      int c4 = (f & 31) << 2;
      *(float4*)&wl[kk][c4] = *(const float4*)&W[(size_t)(k0 + kk) * HDIM + c4];
    }
    __syncthreads();
#pragma unroll
    for (int kk = 0; kk < 32; kk++) {
      float4 a4 = *(const float4*)&xT[kk][r0];
      float4 b0 = *(const float4*)&wl[kk][c0];
      float4 b1 = *(const float4*)&wl[kk][c0 + 4];
      float av[4] = {a4.x, a4.y, a4.z, a4.w};
      float bv[8] = {b0.x, b0.y, b0.z, b0.w, b1.x, b1.y, b1.z, b1.w};
#pragma unroll
      for (int i = 0; i < 4; i++)
#pragma unroll
        for (int j = 0; j < 8; j++) acc[i][j] = fmaf(av[i], bv[j], acc[i][j]);
    }
    __syncthreads();
  }
#pragma unroll
  for (int i = 0; i < 4; i++) {
    float4 s0 = make_float4(acc[i][0], acc[i][1], acc[i][2], acc[i][3]);
    float4 s1 = make_float4(acc[i][4], acc[i][5], acc[i][6], acc[i][7]);
    float* cp = &C[(row0 + r0 + i) * HDIM + c0];
    *(float4*)cp = s0;
    *(float4*)(cp + 4) = s1;
  }
}

// ---------------------------------------------------------------- degree -> dinv (block per graph)
__global__ __launch_bounds__(256) void k_degdinv(const int* __restrict__ dst,
                                                 const float* __restrict__ we,
                                                 float* __restrict__ dinv, int n) {
  __shared__ float dg[256];
  int g = blockIdx.x, t = threadIdx.x;
  if (t < n) dg[t] = 1.0f;                  // self loop
  __syncthreads();
  int eb = g * EPG;
  for (int e = t; e < EPG; e += 256) {
    float w = we[eb + e];
    if (w != 0.f) atomicAdd(&dg[dst[eb + e] - g * n], w);
  }
  __syncthreads();
  if (t < n) dinv[g * n + t] = rsqrtf(dg[t]);
}

// ---------------------------------------------------------------- aggregate + self + bias + relu
// grid (G, 2): block handles 64 of the 128 cols of one graph. LDS accumulator n x 64.
__global__ __launch_bounds__(256) void k_agg(const float* __restrict__ h,
                                             const int* __restrict__ src,
                                             const int* __restrict__ dst,
                                             const float* __restrict__ we,
                                             const float* __restrict__ dinv,
                                             const float* __restrict__ bias,
                                             float* __restrict__ outp, int n) {
  __shared__ float s[256 * 64];             // 64 KB
  int g = blockIdx.x;
  int c0 = blockIdx.y * 64;
  int t = threadIdx.x;
  int lane = t & 63, wv = t >> 6;
  for (int i = t; i < n * 64; i += 256) s[i] = 0.f;
  __syncthreads();
  int eb = g * EPG;
  for (int e = wv; e < EPG; e += 4) {       // wave-uniform edge
    float w = we[eb + e];
    if (w != 0.f) {
      int sg = src[eb + e], dg = dst[eb + e];
      float nrm = w * dinv[sg] * dinv[dg];
      float v = h[(size_t)sg * HDIM + c0 + lane] * nrm;
      atomicAdd(&s[(dg - g * n) * 64 + lane], v);
    }
  }
  __syncthreads();
  for (int i = t; i < n * 64; i += 256) {
    int ln = i >> 6, c = (i & 63) + c0;
    int node = g * n + ln;
    float di = dinv[node];
    float v = s[i] + h[(size_t)node * HDIM + c] * di * di + bias[c];
    outp[(size_t)node * HDIM + c] = fmaxf(v, 0.f);
  }
}

// ---------------------------------------------------------------- TopK pooling (block per graph)
__global__ __launch_bounds__(256) void k_topk(const float* __restrict__ h,
                                              const float* __restrict__ p,
                                              float* __restrict__ pooled,
                                              int* __restrict__ nmap, int n, int k) {
  __shared__ float pl[HDIM];
  __shared__ float sc[256];
  __shared__ int id[256];
  __shared__ float tn[256];
  __shared__ float snorm;
  int g = blockIdx.x, t = threadIdx.x;
  if (t < HDIM) pl[t] = p[t];
  __syncthreads();
  if (t < 64) {                             // ||p|| (deterministic)
    float q = pl[t] * pl[t] + pl[t + 64] * pl[t + 64];
    for (int o = 32; o > 0; o >>= 1) q += __shfl_down(q, o);
    if (t == 0) snorm = sqrtf(q);
  }
  __syncthreads();
  float s = -INFINITY;
  if (t < n) {
    const float* row = h + (size_t)(g * n + t) * HDIM;
    float d = 0.f;
#pragma unroll
    for (int j = 0; j < HDIM; j += 4) {
      float4 v = *(const float4*)&row[j];
      d += v.x * pl[j] + v.y * pl[j + 1] + v.z * pl[j + 2] + v.w * pl[j + 3];
    }
    s = d / snorm;
  }
  sc[t] = s; id[t] = t;
  // bitonic sort, "before" = (score desc, idx asc) to match jax.lax.top_k
  for (int size = 2; size <= 256; size <<= 1)
    for (int stride = size >> 1; stride > 0; stride >>= 1) {
      __syncthreads();
      int j = t ^ stride;
      if (j > t) {
        float s1 = sc[t], s2 = sc[j];
        int i1 = id[t], i2 = id[j];
        bool before = (s1 > s2) || (s1 == s2 && i1 < i2);
        bool wantBefore = ((t & size) == 0);
        if (before != wantBefore) { sc[t] = s2; id[t] = i2; sc[j] = s1; id[j] = i1; }
      }
    }
  __syncthreads();
  if (t < n) nmap[g * n + t] = -1;
  if (t < k) tn[t] = tanhf(sc[t]);
  __syncthreads();
  if (t < k) nmap[g * n + id[t]] = g * k + t;
  for (int i = t; i < k * HDIM; i += 256) {
    int r = i >> 7, c = i & 127;
    pooled[(size_t)(g * k + r) * HDIM + c] =
        h[(size_t)(g * n + id[r]) * HDIM + c] * tn[r];
  }
}

// ---------------------------------------------------------------- edge remap
__global__ __launch_bounds__(256) void k_remap(int* __restrict__ src, int* __restrict__ dst,
                                               float* __restrict__ we,
                                               const int* __restrict__ nmap) {
  int e = blockIdx.x * 256 + threadIdx.x;
  int ms = nmap[src[e]], md = nmap[dst[e]];
  bool v = (ms >= 0) && (md >= 0);
  src[e] = v ? ms : 0;
  dst[e] = v ? md : 0;
  if (!v) we[e] = 0.f;
}

// ---------------------------------------------------------------- global attention pool (block per graph)
__global__ __launch_bounds__(256) void k_attpool(const float* __restrict__ h,
                                                 const float* __restrict__ Wg,
                                                 const float* __restrict__ bgp,
                                                 float* __restrict__ outp, int n, int accflag) {
  __shared__ float wl[HDIM];
  __shared__ float red[256];
  __shared__ float aa[256];
  int g = blockIdx.x, t = threadIdx.x;
  if (t < HDIM) wl[t] = Wg[t];
  __syncthreads();
  float gate = -INFINITY;
  if (t < n) {
    const float* row = h + (size_t)(g * n + t) * HDIM;
    float d = 0.f;
#pragma unroll
    for (int j = 0; j < HDIM; j += 4) {
      float4 v = *(const float4*)&row[j];
      d += v.x * wl[j] + v.y * wl[j + 1] + v.z * wl[j + 2] + v.w * wl[j + 3];
    }
    gate = d + bgp[0];
  }
  red[t] = gate;
  __syncthreads();
  for (int s2 = 128; s2 > 0; s2 >>= 1) {
    if (t < s2) red[t] = fmaxf(red[t], red[t + s2]);
    __syncthreads();
  }
  float m = red[0];
  __syncthreads();
  float ex = (t < n) ? expf(gate - m) : 0.f;
  red[t] = ex;
  __syncthreads();
  for (int s2 = 128; s2 > 0; s2 >>= 1) {
    if (t < s2) red[t] += red[t + s2];
    __syncthreads();
  }
  float inv = 1.f / red[0];
  aa[t] = ex * inv;
  __syncthreads();
  if (t < HDIM) {
    float a2 = 0.f;
    for (int r = 0; r < n; r++) a2 += aa[r] * h[(size_t)(g * n + r) * HDIM + t];
    size_t o = (size_t)g * HDIM + t;
    outp[o] = accflag ? (outp[o] + a2) : a2;
  }
}

// ================================================================ launch
extern "C" void kernel_launch(void* const* d_in, const int* in_sizes, int n_in,
                              void* d_out, int out_size, void* d_ws, size_t ws_size,
                              hipStream_t stream) {
  const float* x  = (const float*)d_in[0];
  const int*   ei = (const int*)d_in[1];
  const float* W0 = (const float*)d_in[2];
  const float* b0 = (const float*)d_in[3];
  const float* p0 = (const float*)d_in[4];
  const float* W1 = (const float*)d_in[5];
  const float* b1 = (const float*)d_in[6];
  const float* p1 = (const float*)d_in[7];
  const float* W2 = (const float*)d_in[8];
  const float* b2 = (const float*)d_in[9];
  const float* p2 = (const float*)d_in[10];
  const float* Wg = (const float*)d_in[11];
  const float* bg = (const float*)d_in[12];
  float* out = (float*)d_out;

  unsigned char* ws = (unsigned char*)d_ws;
  float* buf0 = (float*)(ws);                        // 64 MB
  float* buf1 = (float*)(ws + 67108864ull);          // 64 MB
  float* dinv = (float*)(ws + 134217728ull);         // 512 KB
  int*   nmap = (int*)  (ws + 134742016ull);         // 512 KB
  int*   srcA = (int*)  (ws + 135266304ull);         // 4 MB
  int*   dstA = (int*)  (ws + 139460608ull);         // 4 MB
  float* weA  = (float*)(ws + 143654912ull);         // 4 MB  (total ~141 MB)

  k_edge_init<<<E_TOTAL / 256, 256, 0, stream>>>(ei, srcA, dstA, weA);

  // ---- layer 0: n=256 -> k=205
  k_gemm<<<131072 / 64, 256, 0, stream>>>(x, W0, buf1);
  k_degdinv<<<GCOUNT, 256, 0, stream>>>(dstA, weA, dinv, 256);
  k_agg<<<dim3(GCOUNT, 2), 256, 0, stream>>>(buf1, srcA, dstA, weA, dinv, b0, buf0, 256);
  k_topk<<<GCOUNT, 256, 0, stream>>>(buf0, p0, buf1, nmap, 256, 205);
  k_remap<<<E_TOTAL / 256, 256, 0, stream>>>(srcA, dstA, weA, nmap);
  k_attpool<<<GCOUNT, 256, 0, stream>>>(buf1, Wg, bg, out, 205, 0);

  // ---- layer 1: n=205 -> k=164
  k_gemm<<<104960 / 64, 256, 0, stream>>>(buf1, W1, buf0);
  k_degdinv<<<GCOUNT, 256, 0, stream>>>(dstA, weA, dinv, 205);
  k_agg<<<dim3(GCOUNT, 2), 256, 0, stream>>>(buf0, srcA, dstA, weA, dinv, b1, buf1, 205);
  k_topk<<<GCOUNT, 256, 0, stream>>>(buf1, p1, buf0, nmap, 205, 164);
  k_remap<<<E_TOTAL / 256, 256, 0, stream>>>(srcA, dstA, weA, nmap);
  k_attpool<<<GCOUNT, 256, 0, stream>>>(buf0, Wg, bg, out, 164, 1);

  // ---- layer 2: n=164 -> k=132
  k_gemm<<<83968 / 64, 256, 0, stream>>>(buf0, W2, buf1);
  k_degdinv<<<GCOUNT, 256, 0, stream>>>(dstA, weA, dinv, 164);
  k_agg<<<dim3(GCOUNT, 2), 256, 0, stream>>>(buf1, srcA, dstA, weA, dinv, b2, buf0, 164);
  k_topk<<<GCOUNT, 256, 0, stream>>>(buf0, p2, buf1, nmap, 164, 132);
  k_remap<<<E_TOTAL / 256, 256, 0, stream>>>(srcA, dstA, weA, nmap);
  k_attpool<<<GCOUNT, 256, 0, stream>>>(buf1, Wg, bg, out, 132, 1);
}

// Round 2
// 580.830 us; speedup vs baseline: 3.2153x; 3.2153x over previous
//
#include <hip/hip_runtime.h>
#include <math.h>

#define GCOUNT 512
#define HDIM 128
#define EPG 2048                 // edge slots per graph (fixed across layers)
#define E_TOTAL (GCOUNT * EPG)   // 1,048,576

// ---------------------------------------------------------------- edge init (copy, all valid)
__global__ __launch_bounds__(256) void k_edge_init(const int* __restrict__ ei,
                                                   int* __restrict__ src,
                                                   int* __restrict__ dst) {
  int e = blockIdx.x * 256 + threadIdx.x;
  src[e] = ei[e];
  dst[e] = ei[E_TOTAL + e];
}

// ---------------------------------------------------------------- GEMM: C[M,128] = A[M,128] @ W[128,128], f32
__global__ __launch_bounds__(256) void k_gemm(const float* __restrict__ A,
                                              const float* __restrict__ W,
                                              float* __restrict__ C) {
  __shared__ float xT[32][68];
  __shared__ float wl[32][132];
  int t = threadIdx.x;
  size_t row0 = (size_t)blockIdx.x * 64;
  int r0 = (t >> 4) << 2;
  int c0 = (t & 15) << 3;
  float acc[4][8];
#pragma unroll
  for (int i = 0; i < 4; i++)
#pragma unroll
    for (int j = 0; j < 8; j++) acc[i][j] = 0.f;

  for (int k0 = 0; k0 < 128; k0 += 32) {
#pragma unroll
    for (int i = 0; i < 2; i++) {
      int f = t + i * 256;
      int r = f >> 3;
      int kk4 = (f & 7) << 2;
      float4 v = *(const float4*)&A[(row0 + r) * HDIM + k0 + kk4];
      xT[kk4 + 0][r] = v.x; xT[kk4 + 1][r] = v.y;
      xT[kk4 + 2][r] = v.z; xT[kk4 + 3][r] = v.w;
    }
#pragma unroll
    for (int i = 0; i < 4; i++) {
      int f = t + i * 256;
      int kk = f >> 5;
      int c4 = (f & 31) << 2;
      *(float4*)&wl[kk][c4] = *(const float4*)&W[(size_t)(k0 + kk) * HDIM + c4];
    }
    __syncthreads();
#pragma unroll
    for (int kk = 0; kk < 32; kk++) {
      float4 a4 = *(const float4*)&xT[kk][r0];
      float4 b0 = *(const float4*)&wl[kk][c0];
      float4 b1 = *(const float4*)&wl[kk][c0 + 4];
      float av[4] = {a4.x, a4.y, a4.z, a4.w};
      float bv[8] = {b0.x, b0.y, b0.z, b0.w, b1.x, b1.y, b1.z, b1.w};
#pragma unroll
      for (int i = 0; i < 4; i++)
#pragma unroll
        for (int j = 0; j < 8; j++) acc[i][j] = fmaf(av[i], bv[j], acc[i][j]);
    }
    __syncthreads();
  }
#pragma unroll
  for (int i = 0; i < 4; i++) {
    float4 s0 = make_float4(acc[i][0], acc[i][1], acc[i][2], acc[i][3]);
    float4 s1 = make_float4(acc[i][4], acc[i][5], acc[i][6], acc[i][7]);
    float* cp = &C[(row0 + r0 + i) * HDIM + c0];
    *(float4*)cp = s0;
    *(float4*)(cp + 4) = s1;
  }
}

// ---------------------------------------------------------------- CSR build per graph (+ dinv)
// counting-sort valid edges (src>=0) by local dst; degree = bucket count (w is 0/1).
__global__ __launch_bounds__(256) void k_build(const int* __restrict__ src,
                                               const int* __restrict__ dst,
                                               int* __restrict__ srcS,
                                               int* __restrict__ rowptr,
                                               float* __restrict__ dinv, int n) {
  __shared__ int cnt[256];
  __shared__ int scan[256];
  __shared__ int sb[256];
  __shared__ int ofs[256];
  int g = blockIdx.x, t = threadIdx.x;
  cnt[t] = 0;
  __syncthreads();
  int eb = g * EPG;
  int base = g * n;
  for (int e = t; e < EPG; e += 256) {
    int s = src[eb + e];
    if (s >= 0) atomicAdd(&cnt[dst[eb + e] - base], 1);
  }
  __syncthreads();
  if (t < n) dinv[base + t] = rsqrtf((float)cnt[t] + 1.0f);
  scan[t] = (t < n) ? cnt[t] : 0;
  __syncthreads();
  int* pin = scan;
  int* pout = sb;
#pragma unroll
  for (int off = 1; off < 256; off <<= 1) {
    pout[t] = pin[t] + ((t >= off) ? pin[t - off] : 0);
    __syncthreads();
    int* tmp = pin; pin = pout; pout = tmp;
  }
  // pin[t] = inclusive scan
  int excl = pin[t] - ((t < n) ? cnt[t] : 0);
  ofs[t] = excl;
  if (t < n) rowptr[g * 256 + t] = excl;
  if (t == n - 1 && n < 256) rowptr[g * 256 + n] = pin[t];
  __syncthreads();
  for (int e = t; e < EPG; e += 256) {
    int s = src[eb + e];
    if (s >= 0) {
      int dl = dst[eb + e] - base;
      int pos = atomicAdd(&ofs[dl], 1);
      srcS[eb + pos] = s;
    }
  }
}

// ---------------------------------------------------------------- CSR gather aggregate + self + bias + relu
// grid (G, 4): 4 waves/block = 2 (node-pair, col-half) units; no LDS accumulator, no atomics.
__global__ __launch_bounds__(256) void k_agg_csr(const float* __restrict__ h,
                                                 const int* __restrict__ srcS,
                                                 const int* __restrict__ rowptr,
                                                 const float* __restrict__ dinv,
                                                 const float* __restrict__ bias,
                                                 float* __restrict__ outp, int n) {
  int g = blockIdx.x;
  int t = threadIdx.x;
  int wv = t >> 6, lane = t & 63;
  int pairId = (blockIdx.y << 1) | (wv >> 1);   // 0..7
  int c = ((wv & 1) << 6) | lane;               // 0..127
  const int* rp = rowptr + g * 256;
  int eb = g * EPG;
  float bc = bias[c];
  for (int d = pairId; d < n; d += 8) {
    int node = g * n + d;
    int beg = rp[d];
    int end = (d == 255) ? EPG : rp[d + 1];     // d==255 only when n==256 (layer 0: all valid)
    float dvd = dinv[node];
    float acc = 0.f;
    int j = beg;
    for (; j + 4 <= end; j += 4) {
      int s0 = srcS[eb + j], s1 = srcS[eb + j + 1];
      int s2 = srcS[eb + j + 2], s3 = srcS[eb + j + 3];
      float n0 = dinv[s0], n1 = dinv[s1], n2 = dinv[s2], n3 = dinv[s3];
      float v0 = h[(size_t)s0 * HDIM + c];
      float v1 = h[(size_t)s1 * HDIM + c];
      float v2 = h[(size_t)s2 * HDIM + c];
      float v3 = h[(size_t)s3 * HDIM + c];
      acc = fmaf(n0 * dvd, v0, acc);
      acc = fmaf(n1 * dvd, v1, acc);
      acc = fmaf(n2 * dvd, v2, acc);
      acc = fmaf(n3 * dvd, v3, acc);
    }
    for (; j < end; j++) {
      int s = srcS[eb + j];
      acc = fmaf(dinv[s] * dvd, h[(size_t)s * HDIM + c], acc);
    }
    float r = acc + h[(size_t)node * HDIM + c] * dvd * dvd + bc;
    outp[(size_t)node * HDIM + c] = fmaxf(r, 0.f);
  }
}

// ---------------------------------------------------------------- TopK pooling (block per graph)
__global__ __launch_bounds__(256) void k_topk(const float* __restrict__ h,
                                              const float* __restrict__ p,
                                              float* __restrict__ pooled,
                                              int* __restrict__ nmap, int n, int k) {
  __shared__ float pl[HDIM];
  __shared__ float sc[256];
  __shared__ int id[256];
  __shared__ float tn[256];
  __shared__ float snorm;
  int g = blockIdx.x, t = threadIdx.x;
  if (t < HDIM) pl[t] = p[t];
  __syncthreads();
  if (t < 64) {
    float q = pl[t] * pl[t] + pl[t + 64] * pl[t + 64];
    for (int o = 32; o > 0; o >>= 1) q += __shfl_down(q, o);
    if (t == 0) snorm = sqrtf(q);
  }
  __syncthreads();
  float s = -INFINITY;
  if (t < n) {
    const float* row = h + (size_t)(g * n + t) * HDIM;
    float d = 0.f;
#pragma unroll
    for (int j = 0; j < HDIM; j += 4) {
      float4 v = *(const float4*)&row[j];
      d += v.x * pl[j] + v.y * pl[j + 1] + v.z * pl[j + 2] + v.w * pl[j + 3];
    }
    s = d / snorm;
  }
  sc[t] = s; id[t] = t;
  for (int size = 2; size <= 256; size <<= 1)
    for (int stride = size >> 1; stride > 0; stride >>= 1) {
      __syncthreads();
      int j = t ^ stride;
      if (j > t) {
        float s1 = sc[t], s2 = sc[j];
        int i1 = id[t], i2 = id[j];
        bool before = (s1 > s2) || (s1 == s2 && i1 < i2);
        bool wantBefore = ((t & size) == 0);
        if (before != wantBefore) { sc[t] = s2; id[t] = i2; sc[j] = s1; id[j] = i1; }
      }
    }
  __syncthreads();
  if (t < n) nmap[g * n + t] = -1;
  if (t < k) tn[t] = tanhf(sc[t]);
  __syncthreads();
  if (t < k) nmap[g * n + id[t]] = g * k + t;
  for (int i = t; i < k * HDIM; i += 256) {
    int r = i >> 7, c = i & 127;
    pooled[(size_t)(g * k + r) * HDIM + c] =
        h[(size_t)(g * n + id[r]) * HDIM + c] * tn[r];
  }
}

// ---------------------------------------------------------------- edge remap (src=-1 marks dead)
__global__ __launch_bounds__(256) void k_remap(int* __restrict__ src, int* __restrict__ dst,
                                               const int* __restrict__ nmap) {
  int e = blockIdx.x * 256 + threadIdx.x;
  int s = src[e];
  if (s < 0) return;
  int ms = nmap[s], md = nmap[dst[e]];
  if (ms >= 0 && md >= 0) { src[e] = ms; dst[e] = md; }
  else src[e] = -1;
}

// ---------------------------------------------------------------- global attention pool (block per graph)
__global__ __launch_bounds__(256) void k_attpool(const float* __restrict__ h,
                                                 const float* __restrict__ Wg,
                                                 const float* __restrict__ bgp,
                                                 float* __restrict__ outp, int n, int accflag) {
  __shared__ float wl[HDIM];
  __shared__ float red[256];
  __shared__ float aa[256];
  int g = blockIdx.x, t = threadIdx.x;
  if (t < HDIM) wl[t] = Wg[t];
  __syncthreads();
  float gate = -INFINITY;
  if (t < n) {
    const float* row = h + (size_t)(g * n + t) * HDIM;
    float d = 0.f;
#pragma unroll
    for (int j = 0; j < HDIM; j += 4) {
      float4 v = *(const float4*)&row[j];
      d += v.x * wl[j] + v.y * wl[j + 1] + v.z * wl[j + 2] + v.w * wl[j + 3];
    }
    gate = d + bgp[0];
  }
  red[t] = gate;
  __syncthreads();
  for (int s2 = 128; s2 > 0; s2 >>= 1) {
    if (t < s2) red[t] = fmaxf(red[t], red[t + s2]);
    __syncthreads();
  }
  float m = red[0];
  __syncthreads();
  float ex = (t < n) ? expf(gate - m) : 0.f;
  red[t] = ex;
  __syncthreads();
  for (int s2 = 128; s2 > 0; s2 >>= 1) {
    if (t < s2) red[t] += red[t + s2];
    __syncthreads();
  }
  float inv = 1.f / red[0];
  aa[t] = ex * inv;
  __syncthreads();
  if (t < HDIM) {
    float a2 = 0.f;
    for (int r = 0; r < n; r++) a2 += aa[r] * h[(size_t)(g * n + r) * HDIM + t];
    size_t o = (size_t)g * HDIM + t;
    outp[o] = accflag ? (outp[o] + a2) : a2;
  }
}

// ================================================================ launch
extern "C" void kernel_launch(void* const* d_in, const int* in_sizes, int n_in,
                              void* d_out, int out_size, void* d_ws, size_t ws_size,
                              hipStream_t stream) {
  const float* x  = (const float*)d_in[0];
  const int*   ei = (const int*)d_in[1];
  const float* W0 = (const float*)d_in[2];
  const float* b0 = (const float*)d_in[3];
  const float* p0 = (const float*)d_in[4];
  const float* W1 = (const float*)d_in[5];
  const float* b1 = (const float*)d_in[6];
  const float* p1 = (const float*)d_in[7];
  const float* W2 = (const float*)d_in[8];
  const float* b2 = (const float*)d_in[9];
  const float* p2 = (const float*)d_in[10];
  const float* Wg = (const float*)d_in[11];
  const float* bg = (const float*)d_in[12];
  float* out = (float*)d_out;

  unsigned char* ws = (unsigned char*)d_ws;
  float* buf0 = (float*)(ws);                         // 64 MB
  float* buf1 = (float*)(ws + 67108864ull);           // 64 MB
  float* dinv = (float*)(ws + 134217728ull);          // 512 KB
  int*   nmrp = (int*)  (ws + 134742016ull);          // 512 KB (nmap & rowptr, disjoint lifetimes)
  int*   srcA = (int*)  (ws + 135266304ull);          // 4 MB
  int*   dstA = (int*)  (ws + 139460608ull);          // 4 MB
  int*   srcS = (int*)  (ws + 143654912ull);          // 4 MB  (total 147,849,216 B, same as R1)

  k_edge_init<<<E_TOTAL / 256, 256, 0, stream>>>(ei, srcA, dstA);

  // ---- layer 0: n=256 -> k=205
  k_gemm<<<131072 / 64, 256, 0, stream>>>(x, W0, buf1);
  k_build<<<GCOUNT, 256, 0, stream>>>(srcA, dstA, srcS, nmrp, dinv, 256);
  k_agg_csr<<<dim3(GCOUNT, 4), 256, 0, stream>>>(buf1, srcS, nmrp, dinv, b0, buf0, 256);
  k_topk<<<GCOUNT, 256, 0, stream>>>(buf0, p0, buf1, nmrp, 256, 205);
  k_remap<<<E_TOTAL / 256, 256, 0, stream>>>(srcA, dstA, nmrp);
  k_attpool<<<GCOUNT, 256, 0, stream>>>(buf1, Wg, bg, out, 205, 0);

  // ---- layer 1: n=205 -> k=164
  k_gemm<<<104960 / 64, 256, 0, stream>>>(buf1, W1, buf0);
  k_build<<<GCOUNT, 256, 0, stream>>>(srcA, dstA, srcS, nmrp, dinv, 205);
  k_agg_csr<<<dim3(GCOUNT, 4), 256, 0, stream>>>(buf0, srcS, nmrp, dinv, b1, buf1, 205);
  k_topk<<<GCOUNT, 256, 0, stream>>>(buf1, p1, buf0, nmrp, 205, 164);
  k_remap<<<E_TOTAL / 256, 256, 0, stream>>>(srcA, dstA, nmrp);
  k_attpool<<<GCOUNT, 256, 0, stream>>>(buf0, Wg, bg, out, 164, 1);

  // ---- layer 2: n=164 -> k=132
  k_gemm<<<83968 / 64, 256, 0, stream>>>(buf0, W2, buf1);
  k_build<<<GCOUNT, 256, 0, stream>>>(srcA, dstA, srcS, nmrp, dinv, 164);
  k_agg_csr<<<dim3(GCOUNT, 4), 256, 0, stream>>>(buf1, srcS, nmrp, dinv, b2, buf0, 164);
  k_topk<<<GCOUNT, 256, 0, stream>>>(buf0, p2, buf1, nmrp, 164, 132);
  k_remap<<<E_TOTAL / 256, 256, 0, stream>>>(srcA, dstA, nmrp);
  k_attpool<<<GCOUNT, 256, 0, stream>>>(buf1, Wg, bg, out, 132, 1);
}

// Round 3
// 461.713 us; speedup vs baseline: 4.0448x; 1.2580x over previous
//
#include <hip/hip_runtime.h>
#include <math.h>

#define GCOUNT 512
#define HDIM 128
#define EPG 2048                 // edge slots per graph (fixed across layers)
#define E_TOTAL (GCOUNT * EPG)   // 1,048,576
#define RPSTRIDE 264             // rowptr ints per graph

// ---------------------------------------------------------------- GEMM: C[M,128] = A[M,128] @ W[128,128], f32
__global__ __launch_bounds__(256) void k_gemm(const float* __restrict__ A,
                                              const float* __restrict__ W,
                                              float* __restrict__ C) {
  __shared__ float xT[32][68];
  __shared__ float wl[32][132];
  int t = threadIdx.x;
  size_t row0 = (size_t)blockIdx.x * 64;
  int r0 = (t >> 4) << 2;
  int c0 = (t & 15) << 3;
  float acc[4][8];
#pragma unroll
  for (int i = 0; i < 4; i++)
#pragma unroll
    for (int j = 0; j < 8; j++) acc[i][j] = 0.f;

  for (int k0 = 0; k0 < 128; k0 += 32) {
#pragma unroll
    for (int i = 0; i < 2; i++) {
      int f = t + i * 256;
      int r = f >> 3;
      int kk4 = (f & 7) << 2;
      float4 v = *(const float4*)&A[(row0 + r) * HDIM + k0 + kk4];
      xT[kk4 + 0][r] = v.x; xT[kk4 + 1][r] = v.y;
      xT[kk4 + 2][r] = v.z; xT[kk4 + 3][r] = v.w;
    }
#pragma unroll
    for (int i = 0; i < 4; i++) {
      int f = t + i * 256;
      int kk = f >> 5;
      int c4 = (f & 31) << 2;
      *(float4*)&wl[kk][c4] = *(const float4*)&W[(size_t)(k0 + kk) * HDIM + c4];
    }
    __syncthreads();
#pragma unroll
    for (int kk = 0; kk < 32; kk++) {
      float4 a4 = *(const float4*)&xT[kk][r0];
      float4 b0 = *(const float4*)&wl[kk][c0];
      float4 b1 = *(const float4*)&wl[kk][c0 + 4];
      float av[4] = {a4.x, a4.y, a4.z, a4.w};
      float bv[8] = {b0.x, b0.y, b0.z, b0.w, b1.x, b1.y, b1.z, b1.w};
#pragma unroll
      for (int i = 0; i < 4; i++)
#pragma unroll
        for (int j = 0; j < 8; j++) acc[i][j] = fmaf(av[i], bv[j], acc[i][j]);
    }
    __syncthreads();
  }
#pragma unroll
  for (int i = 0; i < 4; i++) {
    float4 s0 = make_float4(acc[i][0], acc[i][1], acc[i][2], acc[i][3]);
    float4 s1 = make_float4(acc[i][4], acc[i][5], acc[i][6], acc[i][7]);
    float* cp = &C[(row0 + r0 + i) * HDIM + c0];
    *(float4*)cp = s0;
    *(float4*)(cp + 4) = s1;
  }
}

// ---------------------------------------------------------------- CSR build per graph (+ dinv)
// counting-sort valid edges (src>=0) by local dst; srcS gets LOCAL u16 ids.
__global__ __launch_bounds__(256) void k_build(const int* __restrict__ src,
                                               const int* __restrict__ dst,
                                               unsigned short* __restrict__ srcS,
                                               int* __restrict__ rowptr,
                                               float* __restrict__ dinv, int n) {
  __shared__ int cnt[256];
  __shared__ int scan[256];
  __shared__ int sb[256];
  __shared__ int ofs[256];
  int g = blockIdx.x, t = threadIdx.x;
  cnt[t] = 0;
  __syncthreads();
  int eb = g * EPG;
  int base = g * n;
  for (int e = t; e < EPG; e += 256) {
    int s = src[eb + e];
    if (s >= 0) atomicAdd(&cnt[dst[eb + e] - base], 1);
  }
  __syncthreads();
  if (t < n) dinv[base + t] = rsqrtf((float)cnt[t] + 1.0f);
  scan[t] = (t < n) ? cnt[t] : 0;
  __syncthreads();
  int* pin = scan;
  int* pout = sb;
#pragma unroll
  for (int off = 1; off < 256; off <<= 1) {
    pout[t] = pin[t] + ((t >= off) ? pin[t - off] : 0);
    __syncthreads();
    int* tmp = pin; pin = pout; pout = tmp;
  }
  int excl = pin[t] - ((t < n) ? cnt[t] : 0);
  ofs[t] = excl;
  if (t < n) rowptr[g * RPSTRIDE + t] = excl;
  if (t == n - 1) rowptr[g * RPSTRIDE + n] = pin[t];
  __syncthreads();
  for (int e = t; e < EPG; e += 256) {
    int s = src[eb + e];
    if (s >= 0) {
      int dl = dst[eb + e] - base;
      int pos = atomicAdd(&ofs[dl], 1);
      srcS[eb + pos] = (unsigned short)(s - base);
    }
  }
}

// ---------------------------------------------------------------- LDS-staged aggregate + bias + relu + topk-score
// block per graph, 1024 threads (16 waves); lane owns 2 columns.
__global__ __launch_bounds__(1024, 1) void k_agg_fused(const float* __restrict__ h,
                                                       const unsigned short* __restrict__ srcS,
                                                       const int* __restrict__ rowptr,
                                                       const float* __restrict__ dinv,
                                                       const float* __restrict__ bias,
                                                       const float* __restrict__ p,
                                                       float* __restrict__ outp,
                                                       float* __restrict__ scores, int n) {
  __shared__ float h_s[256 * HDIM];          // 128 KB
  __shared__ unsigned short ss_s[EPG];       // 4 KB
  __shared__ int rp_s[257];
  __shared__ float dinv_s[256];
  int g = blockIdx.x, t = threadIdx.x;
  int lane = t & 63, wv = t >> 6;
  // stage h tile (float4)
  const float4* hg = (const float4*)(h + (size_t)g * n * HDIM);
  int n32 = n * 32;
  for (int i = t; i < n32; i += 1024) ((float4*)h_s)[i] = hg[i];
  // stage edges (u16 x8 per int4)
  const int4* sg4 = (const int4*)(srcS + g * EPG);
  for (int i = t; i < EPG / 8; i += 1024) ((int4*)ss_s)[i] = sg4[i];
  if (t < n + 1) rp_s[t] = rowptr[g * RPSTRIDE + t];
  if (t < n) dinv_s[t] = dinv[g * n + t];
  __syncthreads();

  int c = lane << 1;
  float b0 = bias[c], b1 = bias[c + 1];
  float p0 = p[c], p1 = p[c + 1];
  for (int d = wv; d < n; d += 16) {
    int beg = rp_s[d], end = rp_s[d + 1];
    float dvd = dinv_s[d];
    float a0 = 0.f, a1 = 0.f;
    int j = beg;
    for (; j + 4 <= end; j += 4) {
      int s0 = ss_s[j], s1 = ss_s[j + 1], s2 = ss_s[j + 2], s3 = ss_s[j + 3];
      float w0 = dinv_s[s0], w1 = dinv_s[s1], w2 = dinv_s[s2], w3 = dinv_s[s3];
      float2 v0 = *(const float2*)&h_s[s0 * HDIM + c];
      float2 v1 = *(const float2*)&h_s[s1 * HDIM + c];
      float2 v2 = *(const float2*)&h_s[s2 * HDIM + c];
      float2 v3 = *(const float2*)&h_s[s3 * HDIM + c];
      a0 = fmaf(w0, v0.x, a0); a1 = fmaf(w0, v0.y, a1);
      a0 = fmaf(w1, v1.x, a0); a1 = fmaf(w1, v1.y, a1);
      a0 = fmaf(w2, v2.x, a0); a1 = fmaf(w2, v2.y, a1);
      a0 = fmaf(w3, v3.x, a0); a1 = fmaf(w3, v3.y, a1);
    }
    for (; j < end; j++) {
      int s = ss_s[j];
      float w = dinv_s[s];
      float2 v = *(const float2*)&h_s[s * HDIM + c];
      a0 = fmaf(w, v.x, a0); a1 = fmaf(w, v.y, a1);
    }
    float2 vs = *(const float2*)&h_s[d * HDIM + c];
    float r0 = fmaxf(fmaf(dvd, fmaf(vs.x, dvd, a0), b0), 0.f);
    float r1 = fmaxf(fmaf(dvd, fmaf(vs.y, dvd, a1), b1), 0.f);
    *(float2*)&outp[(size_t)(g * n + d) * HDIM + c] = make_float2(r0, r1);
    // fused TopK score: raw dot with p (divide by ||p|| later in k_topk)
    float sc = fmaf(r0, p0, r1 * p1);
#pragma unroll
    for (int o = 32; o > 0; o >>= 1) sc += __shfl_xor(sc, o);
    if (lane == 0) scores[g * n + d] = sc;
  }
}

// ---------------------------------------------------------------- TopK pooling (block per graph)
// scores precomputed (raw dot); nmap may alias scores (reads complete pre-write).
__global__ __launch_bounds__(256) void k_topk(const float* __restrict__ h,
                                              const float* __restrict__ p,
                                              const float* scoresIn,
                                              float* __restrict__ pooled,
                                              int* nmap, int n, int k) {
  __shared__ float sc[256];
  __shared__ int id[256];
  __shared__ float tn[256];
  __shared__ float snorm;
  int g = blockIdx.x, t = threadIdx.x;
  if (t < 64) {
    float q = p[t] * p[t] + p[t + 64] * p[t + 64];
    for (int o = 32; o > 0; o >>= 1) q += __shfl_down(q, o);
    if (t == 0) snorm = sqrtf(q);
  }
  float sraw = (t < n) ? scoresIn[g * n + t] : 0.f;
  __syncthreads();
  sc[t] = (t < n) ? (sraw / snorm) : -INFINITY;
  id[t] = t;
  for (int size = 2; size <= 256; size <<= 1)
    for (int stride = size >> 1; stride > 0; stride >>= 1) {
      __syncthreads();
      int j = t ^ stride;
      if (j > t) {
        float s1 = sc[t], s2 = sc[j];
        int i1 = id[t], i2 = id[j];
        bool before = (s1 > s2) || (s1 == s2 && i1 < i2);
        bool wantBefore = ((t & size) == 0);
        if (before != wantBefore) { sc[t] = s2; id[t] = i2; sc[j] = s1; id[j] = i1; }
      }
    }
  __syncthreads();
  if (t < n) nmap[g * n + t] = -1;
  if (t < k) tn[t] = tanhf(sc[t]);
  __syncthreads();
  if (t < k) nmap[g * n + id[t]] = g * k + t;
  for (int i = t; i < k * HDIM; i += 256) {
    int r = i >> 7, c = i & 127;
    pooled[(size_t)(g * k + r) * HDIM + c] =
        h[(size_t)(g * n + id[r]) * HDIM + c] * tn[r];
  }
}

// ---------------------------------------------------------------- edge remap (src=-1 marks dead)
__global__ __launch_bounds__(256) void k_remap(const int* __restrict__ si,
                                               const int* __restrict__ di,
                                               int* so, int* do_,
                                               const int* __restrict__ nmap) {
  int e = blockIdx.x * 256 + threadIdx.x;
  int s = si[e];
  if (s < 0) { so[e] = -1; return; }
  int ms = nmap[s], md = nmap[di[e]];
  if (ms >= 0 && md >= 0) { so[e] = ms; do_[e] = md; }
  else so[e] = -1;
}

// ---------------------------------------------------------------- global attention pool (block per graph)
__global__ __launch_bounds__(256) void k_attpool(const float* __restrict__ h,
                                                 const float* __restrict__ Wg,
                                                 const float* __restrict__ bgp,
                                                 float* __restrict__ outp, int n, int accflag) {
  __shared__ float wl[HDIM];
  __shared__ float red[256];
  __shared__ float aa[256];
  int g = blockIdx.x, t = threadIdx.x;
  if (t < HDIM) wl[t] = Wg[t];
  __syncthreads();
  float gate = -INFINITY;
  if (t < n) {
    const float* row = h + (size_t)(g * n + t) * HDIM;
    float d = 0.f;
#pragma unroll
    for (int j = 0; j < HDIM; j += 4) {
      float4 v = *(const float4*)&row[j];
      d += v.x * wl[j] + v.y * wl[j + 1] + v.z * wl[j + 2] + v.w * wl[j + 3];
    }
    gate = d + bgp[0];
  }
  red[t] = gate;
  __syncthreads();
  for (int s2 = 128; s2 > 0; s2 >>= 1) {
    if (t < s2) red[t] = fmaxf(red[t], red[t + s2]);
    __syncthreads();
  }
  float m = red[0];
  __syncthreads();
  float ex = (t < n) ? expf(gate - m) : 0.f;
  red[t] = ex;
  __syncthreads();
  for (int s2 = 128; s2 > 0; s2 >>= 1) {
    if (t < s2) red[t] += red[t + s2];
    __syncthreads();
  }
  float inv = 1.f / red[0];
  aa[t] = ex * inv;
  __syncthreads();
  if (t < HDIM) {
    float a2 = 0.f;
    for (int r = 0; r < n; r++) a2 += aa[r] * h[(size_t)(g * n + r) * HDIM + t];
    size_t o = (size_t)g * HDIM + t;
    outp[o] = accflag ? (outp[o] + a2) : a2;
  }
}

// ================================================================ launch
extern "C" void kernel_launch(void* const* d_in, const int* in_sizes, int n_in,
                              void* d_out, int out_size, void* d_ws, size_t ws_size,
                              hipStream_t stream) {
  const float* x  = (const float*)d_in[0];
  const int*   ei = (const int*)d_in[1];
  const float* W0 = (const float*)d_in[2];
  const float* b0 = (const float*)d_in[3];
  const float* p0 = (const float*)d_in[4];
  const float* W1 = (const float*)d_in[5];
  const float* b1 = (const float*)d_in[6];
  const float* p1 = (const float*)d_in[7];
  const float* W2 = (const float*)d_in[8];
  const float* b2 = (const float*)d_in[9];
  const float* p2 = (const float*)d_in[10];
  const float* Wg = (const float*)d_in[11];
  const float* bg = (const float*)d_in[12];
  float* out = (float*)d_out;

  unsigned char* ws = (unsigned char*)d_ws;
  float* buf0 = (float*)(ws);                             // 64 MB
  float* buf1 = (float*)(ws + 67108864ull);               // 64 MB
  float* dinv = (float*)(ws + 134217728ull);              // 512 KB
  int*   nmsc = (int*)  (ws + 134742016ull);              // 512 KB (scores + nmap alias)
  int*   rptr = (int*)  (ws + 135266304ull);              // 540,672 B
  int*   srcA = (int*)  (ws + 135806976ull);              // 4 MB
  int*   dstA = (int*)  (ws + 140001280ull);              // 4 MB
  unsigned short* srcS = (unsigned short*)(ws + 144195584ull); // 2 MB (total 146,292,736)
  float* scrf = (float*)nmsc;

  // ---- layer 0: n=256 -> k=205
  k_gemm<<<131072 / 64, 256, 0, stream>>>(x, W0, buf1);
  k_build<<<GCOUNT, 256, 0, stream>>>(ei, ei + E_TOTAL, srcS, rptr, dinv, 256);
  k_agg_fused<<<GCOUNT, 1024, 0, stream>>>(buf1, srcS, rptr, dinv, b0, p0, buf0, scrf, 256);
  k_topk<<<GCOUNT, 256, 0, stream>>>(buf0, p0, scrf, buf1, nmsc, 256, 205);
  k_remap<<<E_TOTAL / 256, 256, 0, stream>>>(ei, ei + E_TOTAL, srcA, dstA, nmsc);
  k_attpool<<<GCOUNT, 256, 0, stream>>>(buf1, Wg, bg, out, 205, 0);

  // ---- layer 1: n=205 -> k=164
  k_gemm<<<104960 / 64, 256, 0, stream>>>(buf1, W1, buf0);
  k_build<<<GCOUNT, 256, 0, stream>>>(srcA, dstA, srcS, rptr, dinv, 205);
  k_agg_fused<<<GCOUNT, 1024, 0, stream>>>(buf0, srcS, rptr, dinv, b1, p1, buf1, scrf, 205);
  k_topk<<<GCOUNT, 256, 0, stream>>>(buf1, p1, scrf, buf0, nmsc, 205, 164);
  k_remap<<<E_TOTAL / 256, 256, 0, stream>>>(srcA, dstA, srcA, dstA, nmsc);
  k_attpool<<<GCOUNT, 256, 0, stream>>>(buf0, Wg, bg, out, 164, 1);

  // ---- layer 2: n=164 -> k=132
  k_gemm<<<83968 / 64, 256, 0, stream>>>(buf0, W2, buf1);
  k_build<<<GCOUNT, 256, 0, stream>>>(srcA, dstA, srcS, rptr, dinv, 164);
  k_agg_fused<<<GCOUNT, 1024, 0, stream>>>(buf1, srcS, rptr, dinv, b2, p2, buf0, scrf, 164);
  k_topk<<<GCOUNT, 256, 0, stream>>>(buf0, p2, scrf, buf1, nmsc, 164, 132);
  k_remap<<<E_TOTAL / 256, 256, 0, stream>>>(srcA, dstA, srcA, dstA, nmsc);
  k_attpool<<<GCOUNT, 256, 0, stream>>>(buf1, Wg, bg, out, 132, 1);
}

// Round 4
// 426.595 us; speedup vs baseline: 4.3778x; 1.0823x over previous
//
#include <hip/hip_runtime.h>
#include <math.h>

#define GCOUNT 512
#define HDIM 128
#define EPG 2048                 // edge slots per graph (fixed across layers)
#define E_TOTAL (GCOUNT * EPG)   // 1,048,576
#define RPSTRIDE 264             // rowptr ints per graph

typedef __attribute__((ext_vector_type(8))) short short8;
typedef __attribute__((ext_vector_type(4))) float f32x4;

__device__ inline unsigned short f2bf(float f) {
  unsigned int u = __float_as_uint(f);
  return (unsigned short)((u + 0x7FFFu + ((u >> 16) & 1u)) >> 16);
}
__device__ inline float bf2f(unsigned short s) {
  return __uint_as_float(((unsigned int)s) << 16);
}

// ---------------------------------------------------------------- W prepack: bf16 3-split, MFMA-B-fragment layout
// out: ushort Ws[s][kc][ct][lane][j]  (3 x 4 x 8 x 64 x 8 = 96 KB)
__global__ __launch_bounds__(256) void k_wsplit(const float* __restrict__ W,
                                                unsigned short* __restrict__ out) {
  int t = blockIdx.x * 256 + threadIdx.x;   // 2048 = (kc*8+ct)*64+lane
  int lane = t & 63;
  int ct = (t >> 6) & 7;
  int kc = t >> 9;
  int kbase = kc * 32 + (lane >> 4) * 8;
  int col = ct * 16 + (lane & 15);
#pragma unroll
  for (int j = 0; j < 8; j++) {
    float w = W[(size_t)(kbase + j) * HDIM + col];
    unsigned short h0 = f2bf(w);  float g0 = bf2f(h0);
    float r1 = w - g0;
    unsigned short h1 = f2bf(r1); float g1 = bf2f(h1);
    unsigned short h2 = f2bf(r1 - g1);
    int base = (kc * 8 + ct) * 512 + lane * 8 + j;
    out[base]         = h0;
    out[base + 16384] = h1;
    out[base + 32768] = h2;
  }
}

// ---------------------------------------------------------------- GEMM via MFMA (6-term bf16 split ~ f32 accuracy)
// block 256 thr = 4 waves; tile 128 rows x 128 cols; wave = 32 rows (2 row-tiles).
__global__ __launch_bounds__(256) void k_gemm_mfma(const float* __restrict__ A,
                                                   const unsigned short* __restrict__ Ws,
                                                   float* __restrict__ C) {
  __shared__ float at[128 * 132];           // ~67.6 KB, stride 132 (2-way banks max)
  int t = threadIdx.x;
  size_t row0 = (size_t)blockIdx.x * 128;
  const float4* ag = (const float4*)(A + row0 * HDIM);
  for (int i = t; i < 128 * 32; i += 256) {
    int r = i >> 5, k4 = (i & 31) << 2;
    *(float4*)&at[r * 132 + k4] = ag[i];
  }
  __syncthreads();
  int lane = t & 63, wv = t >> 6;
  int rbase = wv * 32;
  f32x4 acc[2][8];
#pragma unroll
  for (int rt = 0; rt < 2; rt++)
#pragma unroll
    for (int ct = 0; ct < 8; ct++) acc[rt][ct] = (f32x4){0.f, 0.f, 0.f, 0.f};

  int arow = lane & 15;
  int kgrp = (lane >> 4) * 8;
#pragma unroll
  for (int kc = 0; kc < 4; kc++) {
    short8 fa0[2], fa1[2], fa2[2];
#pragma unroll
    for (int rt = 0; rt < 2; rt++) {
      const float* ap = &at[(rbase + rt * 16 + arow) * 132 + kc * 32 + kgrp];
      float4 x0 = *(const float4*)ap;
      float4 x1 = *(const float4*)(ap + 4);
      float v[8] = {x0.x, x0.y, x0.z, x0.w, x1.x, x1.y, x1.z, x1.w};
#pragma unroll
      for (int j = 0; j < 8; j++) {
        float a = v[j];
        unsigned short h0 = f2bf(a);  float g0 = bf2f(h0);
        float r1 = a - g0;
        unsigned short h1 = f2bf(r1); float g1 = bf2f(h1);
        unsigned short h2 = f2bf(r1 - g1);
        fa0[rt][j] = (short)h0; fa1[rt][j] = (short)h1; fa2[rt][j] = (short)h2;
      }
    }
    const unsigned short* wb = Ws + (size_t)kc * 8 * 512 + lane * 8;
#pragma unroll
    for (int ct = 0; ct < 8; ct++) {
      short8 b0 = *(const short8*)(wb + ct * 512);
      short8 b1 = *(const short8*)(wb + 16384 + ct * 512);
      short8 b2 = *(const short8*)(wb + 32768 + ct * 512);
#pragma unroll
      for (int rt = 0; rt < 2; rt++) {
        acc[rt][ct] = __builtin_amdgcn_mfma_f32_16x16x32_bf16(fa0[rt], b0, acc[rt][ct], 0, 0, 0);
        acc[rt][ct] = __builtin_amdgcn_mfma_f32_16x16x32_bf16(fa0[rt], b1, acc[rt][ct], 0, 0, 0);
        acc[rt][ct] = __builtin_amdgcn_mfma_f32_16x16x32_bf16(fa1[rt], b0, acc[rt][ct], 0, 0, 0);
        acc[rt][ct] = __builtin_amdgcn_mfma_f32_16x16x32_bf16(fa1[rt], b1, acc[rt][ct], 0, 0, 0);
        acc[rt][ct] = __builtin_amdgcn_mfma_f32_16x16x32_bf16(fa0[rt], b2, acc[rt][ct], 0, 0, 0);
        acc[rt][ct] = __builtin_amdgcn_mfma_f32_16x16x32_bf16(fa2[rt], b0, acc[rt][ct], 0, 0, 0);
      }
    }
  }
  int crow = (lane >> 4) * 4;
  int ccol = lane & 15;
#pragma unroll
  for (int rt = 0; rt < 2; rt++)
#pragma unroll
    for (int ct = 0; ct < 8; ct++)
#pragma unroll
      for (int reg = 0; reg < 4; reg++)
        C[(row0 + rbase + rt * 16 + crow + reg) * HDIM + ct * 16 + ccol] = acc[rt][ct][reg];
}

// ---------------------------------------------------------------- CSR build per graph (+ dinv)
__global__ __launch_bounds__(256) void k_build(const int* __restrict__ src,
                                               const int* __restrict__ dst,
                                               unsigned short* __restrict__ srcS,
                                               int* __restrict__ rowptr,
                                               float* __restrict__ dinv, int n) {
  __shared__ int cnt[256];
  __shared__ int scan[256];
  __shared__ int sb[256];
  __shared__ int ofs[256];
  int g = blockIdx.x, t = threadIdx.x;
  cnt[t] = 0;
  __syncthreads();
  int eb = g * EPG;
  int base = g * n;
  for (int e = t; e < EPG; e += 256) {
    int s = src[eb + e];
    if (s >= 0) atomicAdd(&cnt[dst[eb + e] - base], 1);
  }
  __syncthreads();
  if (t < n) dinv[base + t] = rsqrtf((float)cnt[t] + 1.0f);
  scan[t] = (t < n) ? cnt[t] : 0;
  __syncthreads();
  int* pin = scan;
  int* pout = sb;
#pragma unroll
  for (int off = 1; off < 256; off <<= 1) {
    pout[t] = pin[t] + ((t >= off) ? pin[t - off] : 0);
    __syncthreads();
    int* tmp = pin; pin = pout; pout = tmp;
  }
  int excl = pin[t] - ((t < n) ? cnt[t] : 0);
  ofs[t] = excl;
  if (t < n) rowptr[g * RPSTRIDE + t] = excl;
  if (t == n - 1) rowptr[g * RPSTRIDE + n] = pin[t];
  __syncthreads();
  for (int e = t; e < EPG; e += 256) {
    int s = src[eb + e];
    if (s >= 0) {
      int dl = dst[eb + e] - base;
      int pos = atomicAdd(&ofs[dl], 1);
      srcS[eb + pos] = (unsigned short)(s - base);
    }
  }
}

// ---------------------------------------------------------------- LDS-staged aggregate + bias + relu + topk-score
__global__ __launch_bounds__(1024, 1) void k_agg_fused(const float* __restrict__ h,
                                                       const unsigned short* __restrict__ srcS,
                                                       const int* __restrict__ rowptr,
                                                       const float* __restrict__ dinv,
                                                       const float* __restrict__ bias,
                                                       const float* __restrict__ p,
                                                       float* __restrict__ outp,
                                                       float* __restrict__ scores, int n) {
  __shared__ float h_s[256 * HDIM];          // 128 KB
  __shared__ unsigned short ss_s[EPG];       // 4 KB
  __shared__ int rp_s[257];
  __shared__ float dinv_s[256];
  int g = blockIdx.x, t = threadIdx.x;
  int lane = t & 63, wv = t >> 6;
  const float4* hg = (const float4*)(h + (size_t)g * n * HDIM);
  int n32 = n * 32;
  for (int i = t; i < n32; i += 1024) ((float4*)h_s)[i] = hg[i];
  const int4* sg4 = (const int4*)(srcS + g * EPG);
  for (int i = t; i < EPG / 8; i += 1024) ((int4*)ss_s)[i] = sg4[i];
  if (t < n + 1) rp_s[t] = rowptr[g * RPSTRIDE + t];
  if (t < n) dinv_s[t] = dinv[g * n + t];
  __syncthreads();

  int c = lane << 1;
  float b0 = bias[c], b1 = bias[c + 1];
  float p0 = p[c], p1 = p[c + 1];
  for (int d = wv; d < n; d += 16) {
    int beg = rp_s[d], end = rp_s[d + 1];
    float dvd = dinv_s[d];
    float a0 = 0.f, a1 = 0.f;
    int j = beg;
    for (; j + 4 <= end; j += 4) {
      int s0 = ss_s[j], s1 = ss_s[j + 1], s2 = ss_s[j + 2], s3 = ss_s[j + 3];
      float w0 = dinv_s[s0], w1 = dinv_s[s1], w2 = dinv_s[s2], w3 = dinv_s[s3];
      float2 v0 = *(const float2*)&h_s[s0 * HDIM + c];
      float2 v1 = *(const float2*)&h_s[s1 * HDIM + c];
      float2 v2 = *(const float2*)&h_s[s2 * HDIM + c];
      float2 v3 = *(const float2*)&h_s[s3 * HDIM + c];
      a0 = fmaf(w0, v0.x, a0); a1 = fmaf(w0, v0.y, a1);
      a0 = fmaf(w1, v1.x, a0); a1 = fmaf(w1, v1.y, a1);
      a0 = fmaf(w2, v2.x, a0); a1 = fmaf(w2, v2.y, a1);
      a0 = fmaf(w3, v3.x, a0); a1 = fmaf(w3, v3.y, a1);
    }
    for (; j < end; j++) {
      int s = ss_s[j];
      float w = dinv_s[s];
      float2 v = *(const float2*)&h_s[s * HDIM + c];
      a0 = fmaf(w, v.x, a0); a1 = fmaf(w, v.y, a1);
    }
    float2 vs = *(const float2*)&h_s[d * HDIM + c];
    float r0 = fmaxf(fmaf(dvd, fmaf(vs.x, dvd, a0), b0), 0.f);
    float r1 = fmaxf(fmaf(dvd, fmaf(vs.y, dvd, a1), b1), 0.f);
    *(float2*)&outp[(size_t)(g * n + d) * HDIM + c] = make_float2(r0, r1);
    float sc = fmaf(r0, p0, r1 * p1);
#pragma unroll
    for (int o = 32; o > 0; o >>= 1) sc += __shfl_xor(sc, o);
    if (lane == 0) scores[g * n + d] = sc;
  }
}

// ---------------------------------------------------------------- TopK pooling (block per graph)
__global__ __launch_bounds__(256) void k_topk(const float* __restrict__ h,
                                              const float* __restrict__ p,
                                              const float* scoresIn,
                                              float* __restrict__ pooled,
                                              int* nmap, int n, int k) {
  __shared__ float sc[256];
  __shared__ int id[256];
  __shared__ float tn[256];
  __shared__ float snorm;
  int g = blockIdx.x, t = threadIdx.x;
  if (t < 64) {
    float q = p[t] * p[t] + p[t + 64] * p[t + 64];
    for (int o = 32; o > 0; o >>= 1) q += __shfl_down(q, o);
    if (t == 0) snorm = sqrtf(q);
  }
  float sraw = (t < n) ? scoresIn[g * n + t] : 0.f;
  __syncthreads();
  sc[t] = (t < n) ? (sraw / snorm) : -INFINITY;
  id[t] = t;
  for (int size = 2; size <= 256; size <<= 1)
    for (int stride = size >> 1; stride > 0; stride >>= 1) {
      __syncthreads();
      int j = t ^ stride;
      if (j > t) {
        float s1 = sc[t], s2 = sc[j];
        int i1 = id[t], i2 = id[j];
        bool before = (s1 > s2) || (s1 == s2 && i1 < i2);
        bool wantBefore = ((t & size) == 0);
        if (before != wantBefore) { sc[t] = s2; id[t] = i2; sc[j] = s1; id[j] = i1; }
      }
    }
  __syncthreads();
  if (t < n) nmap[g * n + t] = -1;
  if (t < k) tn[t] = tanhf(sc[t]);
  __syncthreads();
  if (t < k) nmap[g * n + id[t]] = g * k + t;
  for (int i = t; i < k * HDIM; i += 256) {
    int r = i >> 7, c = i & 127;
    pooled[(size_t)(g * k + r) * HDIM + c] =
        h[(size_t)(g * n + id[r]) * HDIM + c] * tn[r];
  }
}

// ---------------------------------------------------------------- edge remap (src=-1 marks dead)
__global__ __launch_bounds__(256) void k_remap(const int* __restrict__ si,
                                               const int* __restrict__ di,
                                               int* so, int* do_,
                                               const int* __restrict__ nmap) {
  int e = blockIdx.x * 256 + threadIdx.x;
  int s = si[e];
  if (s < 0) { so[e] = -1; return; }
  int ms = nmap[s], md = nmap[di[e]];
  if (ms >= 0 && md >= 0) { so[e] = ms; do_[e] = md; }
  else so[e] = -1;
}

// ---------------------------------------------------------------- global attention pool (block per graph)
__global__ __launch_bounds__(256) void k_attpool(const float* __restrict__ h,
                                                 const float* __restrict__ Wg,
                                                 const float* __restrict__ bgp,
                                                 float* __restrict__ outp, int n, int accflag) {
  __shared__ float wl[HDIM];
  __shared__ float red[256];
  __shared__ float aa[256];
  int g = blockIdx.x, t = threadIdx.x;
  if (t < HDIM) wl[t] = Wg[t];
  __syncthreads();
  float gate = -INFINITY;
  if (t < n) {
    const float* row = h + (size_t)(g * n + t) * HDIM;
    float d = 0.f;
#pragma unroll
    for (int j = 0; j < HDIM; j += 4) {
      float4 v = *(const float4*)&row[j];
      d += v.x * wl[j] + v.y * wl[j + 1] + v.z * wl[j + 2] + v.w * wl[j + 3];
    }
    gate = d + bgp[0];
  }
  red[t] = gate;
  __syncthreads();
  for (int s2 = 128; s2 > 0; s2 >>= 1) {
    if (t < s2) red[t] = fmaxf(red[t], red[t + s2]);
    __syncthreads();
  }
  float m = red[0];
  __syncthreads();
  float ex = (t < n) ? expf(gate - m) : 0.f;
  red[t] = ex;
  __syncthreads();
  for (int s2 = 128; s2 > 0; s2 >>= 1) {
    if (t < s2) red[t] += red[t + s2];
    __syncthreads();
  }
  float inv = 1.f / red[0];
  aa[t] = ex * inv;
  __syncthreads();
  if (t < HDIM) {
    float a2 = 0.f;
    for (int r = 0; r < n; r++) a2 += aa[r] * h[(size_t)(g * n + r) * HDIM + t];
    size_t o = (size_t)g * HDIM + t;
    outp[o] = accflag ? (outp[o] + a2) : a2;
  }
}

// ================================================================ launch
extern "C" void kernel_launch(void* const* d_in, const int* in_sizes, int n_in,
                              void* d_out, int out_size, void* d_ws, size_t ws_size,
                              hipStream_t stream) {
  const float* x  = (const float*)d_in[0];
  const int*   ei = (const int*)d_in[1];
  const float* W0 = (const float*)d_in[2];
  const float* b0 = (const float*)d_in[3];
  const float* p0 = (const float*)d_in[4];
  const float* W1 = (const float*)d_in[5];
  const float* b1 = (const float*)d_in[6];
  const float* p1 = (const float*)d_in[7];
  const float* W2 = (const float*)d_in[8];
  const float* b2 = (const float*)d_in[9];
  const float* p2 = (const float*)d_in[10];
  const float* Wg = (const float*)d_in[11];
  const float* bg = (const float*)d_in[12];
  float* out = (float*)d_out;

  unsigned char* ws = (unsigned char*)d_ws;
  float* buf0 = (float*)(ws);                             // 64 MB
  float* buf1 = (float*)(ws + 67108864ull);               // 64 MB
  float* dinv = (float*)(ws + 134217728ull);              // 512 KB
  int*   nmsc = (int*)  (ws + 134742016ull);              // 512 KB (scores + nmap alias)
  int*   rptr = (int*)  (ws + 135266304ull);              // 540,672 B
  int*   srcA = (int*)  (ws + 135806976ull);              // 4 MB
  int*   dstA = (int*)  (ws + 140001280ull);              // 4 MB
  unsigned short* srcS = (unsigned short*)(ws + 144195584ull); // 2 MB
  unsigned short* Wsp  = (unsigned short*)(ws + 146292736ull); // 96 KB (total ~146.4 MB)
  float* scrf = (float*)nmsc;

  // ---- layer 0: n=256 -> k=205
  k_wsplit<<<8, 256, 0, stream>>>(W0, Wsp);
  k_gemm_mfma<<<131072 / 128, 256, 0, stream>>>(x, Wsp, buf1);
  k_build<<<GCOUNT, 256, 0, stream>>>(ei, ei + E_TOTAL, srcS, rptr, dinv, 256);
  k_agg_fused<<<GCOUNT, 1024, 0, stream>>>(buf1, srcS, rptr, dinv, b0, p0, buf0, scrf, 256);
  k_topk<<<GCOUNT, 256, 0, stream>>>(buf0, p0, scrf, buf1, nmsc, 256, 205);
  k_remap<<<E_TOTAL / 256, 256, 0, stream>>>(ei, ei + E_TOTAL, srcA, dstA, nmsc);
  k_attpool<<<GCOUNT, 256, 0, stream>>>(buf1, Wg, bg, out, 205, 0);

  // ---- layer 1: n=205 -> k=164
  k_wsplit<<<8, 256, 0, stream>>>(W1, Wsp);
  k_gemm_mfma<<<104960 / 128, 256, 0, stream>>>(buf1, Wsp, buf0);
  k_build<<<GCOUNT, 256, 0, stream>>>(srcA, dstA, srcS, rptr, dinv, 205);
  k_agg_fused<<<GCOUNT, 1024, 0, stream>>>(buf0, srcS, rptr, dinv, b1, p1, buf1, scrf, 205);
  k_topk<<<GCOUNT, 256, 0, stream>>>(buf1, p1, scrf, buf0, nmsc, 205, 164);
  k_remap<<<E_TOTAL / 256, 256, 0, stream>>>(srcA, dstA, srcA, dstA, nmsc);
  k_attpool<<<GCOUNT, 256, 0, stream>>>(buf0, Wg, bg, out, 164, 1);

  // ---- layer 2: n=164 -> k=132
  k_wsplit<<<8, 256, 0, stream>>>(W2, Wsp);
  k_gemm_mfma<<<83968 / 128, 256, 0, stream>>>(buf0, Wsp, buf1);
  k_build<<<GCOUNT, 256, 0, stream>>>(srcA, dstA, srcS, rptr, dinv, 164);
  k_agg_fused<<<GCOUNT, 1024, 0, stream>>>(buf1, srcS, rptr, dinv, b2, p2, buf0, scrf, 164);
  k_topk<<<GCOUNT, 256, 0, stream>>>(buf0, p2, scrf, buf1, nmsc, 164, 132);
  k_remap<<<E_TOTAL / 256, 256, 0, stream>>>(srcA, dstA, srcA, dstA, nmsc);
  k_attpool<<<GCOUNT, 256, 0, stream>>>(buf1, Wg, bg, out, 132, 1);
}

// Round 5
// 300.153 us; speedup vs baseline: 6.2220x; 1.4213x over previous
//
#include <hip/hip_runtime.h>
#include <math.h>

#define GCOUNT 512
#define HDIM 128
#define EPG 2048                 // edge slots per graph (fixed across layers)
#define E_TOTAL (GCOUNT * EPG)   // 1,048,576

typedef __attribute__((ext_vector_type(8))) short short8;
typedef __attribute__((ext_vector_type(4))) float f32x4;

__device__ inline unsigned short f2bf(float f) {
  unsigned int u = __float_as_uint(f);
  return (unsigned short)((u + 0x7FFFu + ((u >> 16) & 1u)) >> 16);
}
__device__ inline float bf2f(unsigned short s) {
  return __uint_as_float(((unsigned int)s) << 16);
}

// ---------------------------------------------------------------- W prepack: bf16 3-split, MFMA-B-fragment layout
// out: ushort Ws[s][kc][ct][lane][j]  (3 x 4 x 8 x 64 x 8 = 96 KB)
__global__ __launch_bounds__(256) void k_wsplit(const float* __restrict__ W,
                                                unsigned short* __restrict__ out) {
  int t = blockIdx.x * 256 + threadIdx.x;   // 2048 = (kc*8+ct)*64+lane
  int lane = t & 63;
  int ct = (t >> 6) & 7;
  int kc = t >> 9;
  int kbase = kc * 32 + (lane >> 4) * 8;
  int col = ct * 16 + (lane & 15);
#pragma unroll
  for (int j = 0; j < 8; j++) {
    float w = W[(size_t)(kbase + j) * HDIM + col];
    unsigned short h0 = f2bf(w);  float g0 = bf2f(h0);
    float r1 = w - g0;
    unsigned short h1 = f2bf(r1); float g1 = bf2f(h1);
    unsigned short h2 = f2bf(r1 - g1);
    int base = (kc * 8 + ct) * 512 + lane * 8 + j;
    out[base]         = h0;
    out[base + 16384] = h1;
    out[base + 32768] = h2;
  }
}

// ---------------------------------------------------------------- fused layer:
// gemm(MFMA) + CSR build + aggregate + relu + topk + pool + attpool + remap,
// one block per graph, 1024 threads, ~158 KB LDS.
__global__ __launch_bounds__(1024, 1) void k_layer(
    const float* __restrict__ xIn, const int* __restrict__ ei0,
    const unsigned int* __restrict__ eIn, unsigned int* __restrict__ eOut,
    float* poolOut, const unsigned short* __restrict__ Ws,
    const float* __restrict__ bias, const float* __restrict__ p,
    const float* __restrict__ Wg, const float* __restrict__ bgp,
    float* outp, int n, int k, int first, int accflag) {

  __shared__ __align__(16) float h_s[256 * 132];   // 135168 B, stride 132
  __shared__ __align__(16) char uni[24576];        // union region
  __shared__ float dinv_s[256];
  __shared__ float rawsc_s[256];
  __shared__ float snorm_s;

  unsigned short* wchunk = (unsigned short*)uni;        // phase B only (24 KB)
  unsigned short* es   = (unsigned short*)uni;          // (src,dst) u16 pairs, 8 KB
  unsigned short* ss   = (unsigned short*)(uni + 8192); // dst-sorted src, 4 KB
  int*   cnt  = (int*)(uni + 12288);                    // degree, later nmap
  int*   scn  = (int*)(uni + 13312);
  int*   sb   = (int*)(uni + 14336);
  int*   ofs  = (int*)(uni + 15360);
  float* sc   = (float*)(uni + 16384);                  // sort keys, later aa
  int*   idx  = (int*)(uni + 17408);
  float* tn   = (float*)(uni + 18432);
  float* red  = (float*)(uni + 19456);
  int*   rp   = (int*)(uni + 20480);                    // rowptr [257]
  float* wg_s = (float*)(uni + 21760);                  // Wg [128]

  int g = blockIdx.x, t = threadIdx.x;
  int lane = t & 63, wv = t >> 6;
  int T = (n + 15) >> 4;                                // 16-row gemm tiles

  // ---- A: stage x (zero-pad to T*16 rows)
  const float4* xg = (const float4*)(xIn + (size_t)g * n * HDIM);
  for (int i = t; i < n * 32; i += 1024) {
    int r = i >> 5, j = i & 31;
    *(float4*)&h_s[r * 132 + (j << 2)] = xg[i];
  }
  for (int i = n * 32 + t; i < T * 16 * 32; i += 1024) {
    int r = i >> 5, j = i & 31;
    *(float4*)&h_s[r * 132 + (j << 2)] = make_float4(0.f, 0.f, 0.f, 0.f);
  }
  __syncthreads();

  // ---- B: gemm h = x @ W (6-term bf16 split), W chunk staged per kc
  int arow = lane & 15, kgrp = (lane >> 4) * 8;
  f32x4 acc[8];
#pragma unroll
  for (int ct = 0; ct < 8; ct++) acc[ct] = (f32x4){0.f, 0.f, 0.f, 0.f};
#pragma unroll 1
  for (int kc = 0; kc < 4; kc++) {
    for (int i = t; i < 1536; i += 1024) {          // 24 KB = 1536 float4
      int b = i >> 6, off = i & 63;
      int s = b >> 3, ct2 = b & 7;
      ((float4*)wchunk)[i] =
          *(const float4*)(Ws + s * 16384 + (kc * 8 + ct2) * 512 + off * 8);
    }
    __syncthreads();
    if (wv < T) {
      const float* ap = &h_s[(wv * 16 + arow) * 132 + kc * 32 + kgrp];
      float4 x0 = *(const float4*)ap;
      float4 x1 = *(const float4*)(ap + 4);
      float v[8] = {x0.x, x0.y, x0.z, x0.w, x1.x, x1.y, x1.z, x1.w};
      short8 fa0, fa1, fa2;
#pragma unroll
      for (int j = 0; j < 8; j++) {
        float a = v[j];
        unsigned short h0 = f2bf(a);  float g0 = bf2f(h0);
        float r1 = a - g0;
        unsigned short h1 = f2bf(r1); float g1 = bf2f(h1);
        unsigned short h2 = f2bf(r1 - g1);
        fa0[j] = (short)h0; fa1[j] = (short)h1; fa2[j] = (short)h2;
      }
#pragma unroll
      for (int ct = 0; ct < 8; ct++) {
        const unsigned short* wb = wchunk + ct * 512 + lane * 8;
        short8 b0 = *(const short8*)wb;
        short8 b1 = *(const short8*)(wb + 4096);
        short8 b2 = *(const short8*)(wb + 8192);
        acc[ct] = __builtin_amdgcn_mfma_f32_16x16x32_bf16(fa0, b0, acc[ct], 0, 0, 0);
        acc[ct] = __builtin_amdgcn_mfma_f32_16x16x32_bf16(fa0, b1, acc[ct], 0, 0, 0);
        acc[ct] = __builtin_amdgcn_mfma_f32_16x16x32_bf16(fa1, b0, acc[ct], 0, 0, 0);
        acc[ct] = __builtin_amdgcn_mfma_f32_16x16x32_bf16(fa1, b1, acc[ct], 0, 0, 0);
        acc[ct] = __builtin_amdgcn_mfma_f32_16x16x32_bf16(fa0, b2, acc[ct], 0, 0, 0);
        acc[ct] = __builtin_amdgcn_mfma_f32_16x16x32_bf16(fa2, b0, acc[ct], 0, 0, 0);
      }
    }
    __syncthreads();
  }
  if (wv < T) {                                     // write h over x (own tile only)
    int crow = (lane >> 4) * 4, ccol = lane & 15;
#pragma unroll
    for (int ct = 0; ct < 8; ct++)
#pragma unroll
      for (int reg = 0; reg < 4; reg++)
        h_s[(wv * 16 + crow + reg) * 132 + ct * 16 + ccol] = acc[ct][reg];
  }

  // ---- stage edges into union (wchunk dead), zero cnt
  int eb = g * EPG;
  if (first) {
    for (int e = t; e < EPG; e += 1024) {
      es[2 * e]     = (unsigned short)(ei0[eb + e] - g * n);
      es[2 * e + 1] = (unsigned short)(ei0[E_TOTAL + eb + e] - g * n);
    }
  } else {
    for (int e = t; e < EPG; e += 1024) {
      unsigned int u = eIn[eb + e];
      es[2 * e]     = (unsigned short)(u & 0xFFFFu);
      es[2 * e + 1] = (unsigned short)(u >> 16);
    }
  }
  if (t < 256) cnt[t] = 0;
  __syncthreads();

  // ---- C: CSR build (counting sort by dst)
  for (int e = t; e < EPG; e += 1024) {
    int s = es[2 * e];
    if (s != 0xFFFF) atomicAdd(&cnt[es[2 * e + 1]], 1);
  }
  __syncthreads();
  if (t < n) dinv_s[t] = rsqrtf((float)cnt[t] + 1.0f);
  if (t < 256) scn[t] = (t < n) ? cnt[t] : 0;
  __syncthreads();
  int* pin = scn;
  int* pout = sb;
  for (int off = 1; off < 256; off <<= 1) {
    if (t < 256) pout[t] = pin[t] + ((t >= off) ? pin[t - off] : 0);
    __syncthreads();
    int* tmp = pin; pin = pout; pout = tmp;
  }
  if (t < 256) {
    int excl = pin[t] - ((t < n) ? cnt[t] : 0);
    ofs[t] = excl;
    if (t < n) rp[t] = excl;
    if (t == n - 1) rp[n] = pin[t];
  }
  __syncthreads();
  for (int e = t; e < EPG; e += 1024) {
    int s = es[2 * e];
    if (s != 0xFFFF) {
      int pos = atomicAdd(&ofs[es[2 * e + 1]], 1);
      ss[pos] = (unsigned short)s;
    }
  }
  __syncthreads();

  // ---- D: aggregate into registers (+self+bias+relu+score), then write back
  int c = lane << 1;
  float bc0 = bias[c], bc1 = bias[c + 1];
  float pc0 = p[c], pc1 = p[c + 1];
  float a0[16], a1[16];
#pragma unroll
  for (int i = 0; i < 16; i++) { a0[i] = 0.f; a1[i] = 0.f; }
#pragma unroll
  for (int i = 0; i < 16; i++) {
    int d = wv + (i << 4);
    if (d < n) {
      int beg = rp[d], end = rp[d + 1];
      float dvd = dinv_s[d];
      float u0 = 0.f, u1 = 0.f;
      int j = beg;
      for (; j + 4 <= end; j += 4) {
        int s0 = ss[j], s1 = ss[j + 1], s2 = ss[j + 2], s3 = ss[j + 3];
        float w0 = dinv_s[s0], w1 = dinv_s[s1], w2 = dinv_s[s2], w3 = dinv_s[s3];
        float2 v0 = *(const float2*)&h_s[s0 * 132 + c];
        float2 v1 = *(const float2*)&h_s[s1 * 132 + c];
        float2 v2 = *(const float2*)&h_s[s2 * 132 + c];
        float2 v3 = *(const float2*)&h_s[s3 * 132 + c];
        u0 = fmaf(w0, v0.x, u0); u1 = fmaf(w0, v0.y, u1);
        u0 = fmaf(w1, v1.x, u0); u1 = fmaf(w1, v1.y, u1);
        u0 = fmaf(w2, v2.x, u0); u1 = fmaf(w2, v2.y, u1);
        u0 = fmaf(w3, v3.x, u0); u1 = fmaf(w3, v3.y, u1);
      }
      for (; j < end; j++) {
        int s = ss[j];
        float w = dinv_s[s];
        float2 v = *(const float2*)&h_s[s * 132 + c];
        u0 = fmaf(w, v.x, u0); u1 = fmaf(w, v.y, u1);
      }
      float2 vs = *(const float2*)&h_s[d * 132 + c];
      float r0 = fmaxf(fmaf(dvd, fmaf(vs.x, dvd, u0), bc0), 0.f);
      float r1 = fmaxf(fmaf(dvd, fmaf(vs.y, dvd, u1), bc1), 0.f);
      a0[i] = r0; a1[i] = r1;
      float scp = fmaf(r0, pc0, r1 * pc1);
#pragma unroll
      for (int o = 32; o > 0; o >>= 1) scp += __shfl_xor(scp, o);
      if (lane == 0) rawsc_s[d] = scp;
    }
  }
  __syncthreads();
#pragma unroll
  for (int i = 0; i < 16; i++) {
    int d = wv + (i << 4);
    if (d < n) {
      h_s[d * 132 + c] = a0[i];
      h_s[d * 132 + c + 1] = a1[i];
    }
  }
  __syncthreads();

  // ---- E: topk sort (first 256 threads; jax tie-break: desc score, asc idx)
  if (t < 64) {
    float q = p[t] * p[t] + p[t + 64] * p[t + 64];
#pragma unroll
    for (int o = 32; o > 0; o >>= 1) q += __shfl_down(q, o);
    if (t == 0) snorm_s = sqrtf(q);
  }
  __syncthreads();
  if (t < 256) {
    sc[t] = (t < n) ? (rawsc_s[t] / snorm_s) : -INFINITY;
    idx[t] = t;
  }
  __syncthreads();
  for (int size = 2; size <= 256; size <<= 1)
    for (int stride = size >> 1; stride > 0; stride >>= 1) {
      if (t < 256) {
        int j2 = t ^ stride;
        if (j2 > t) {
          float s1 = sc[t], s2 = sc[j2];
          int i1 = idx[t], i2 = idx[j2];
          bool before = (s1 > s2) || (s1 == s2 && i1 < i2);
          bool wantBefore = ((t & size) == 0);
          if (before != wantBefore) {
            sc[t] = s2; idx[t] = i2; sc[j2] = s1; idx[j2] = i1;
          }
        }
      }
      __syncthreads();
    }
  if (t < k) tn[t] = tanhf(sc[t]);
  if (t < 256) cnt[t] = -1;                 // cnt reused as nmap
  if (t < HDIM) wg_s[t] = Wg[t];
  __syncthreads();
  if (t < k) cnt[idx[t]] = t;               // new local id
  __syncthreads();

  // ---- F: pooled write + remap + attention pool
  if (poolOut) {
    float4* pg = (float4*)(poolOut + (size_t)g * k * HDIM);
    for (int i = t; i < k * 32; i += 1024) {
      int r = i >> 5, j = i & 31;
      float4 v = *(const float4*)&h_s[idx[r] * 132 + (j << 2)];
      float tnr = tn[r];
      v.x *= tnr; v.y *= tnr; v.z *= tnr; v.w *= tnr;
      pg[i] = v;
    }
  }
  for (int e = t; e < EPG; e += 1024) {
    int s = es[2 * e];
    unsigned int o = 0xFFFFFFFFu;
    if (s != 0xFFFF) {
      int ns = cnt[s], nd = cnt[es[2 * e + 1]];
      if (ns >= 0 && nd >= 0) o = (unsigned int)ns | ((unsigned int)nd << 16);
    }
    eOut[eb + e] = o;
  }
  float gate = 0.f;
  if (t < 256 && t < k) {
    const float* hr = &h_s[idx[t] * 132];
    float dsum = 0.f;
#pragma unroll
    for (int j = 0; j < HDIM; j += 4) {
      float4 v = *(const float4*)&hr[j];
      dsum += v.x * wg_s[j] + v.y * wg_s[j + 1] + v.z * wg_s[j + 2] + v.w * wg_s[j + 3];
    }
    gate = dsum * tn[t] + bgp[0];
  }
  if (t < 256) red[t] = (t < k) ? gate : -INFINITY;
  __syncthreads();
  for (int s2 = 128; s2 > 0; s2 >>= 1) {
    if (t < s2) red[t] = fmaxf(red[t], red[t + s2]);
    __syncthreads();
  }
  float m = red[0];
  __syncthreads();
  float ex = (t < 256 && t < k) ? __expf(gate - m) : 0.f;
  if (t < 256) red[t] = ex;
  __syncthreads();
  for (int s2 = 128; s2 > 0; s2 >>= 1) {
    if (t < s2) red[t] += red[t + s2];
    __syncthreads();
  }
  float inv = 1.f / red[0];
  if (t < 256) sc[t] = ex * inv;            // sc reused as attention weights
  __syncthreads();
  if (t < HDIM) {
    float a2 = 0.f;
    for (int r = 0; r < k; r++) a2 = fmaf(sc[r] * tn[r], h_s[idx[r] * 132 + t], a2);
    size_t o = (size_t)g * HDIM + t;
    outp[o] = accflag ? (outp[o] + a2) : a2;
  }
}

// ================================================================ launch
extern "C" void kernel_launch(void* const* d_in, const int* in_sizes, int n_in,
                              void* d_out, int out_size, void* d_ws, size_t ws_size,
                              hipStream_t stream) {
  const float* x  = (const float*)d_in[0];
  const int*   ei = (const int*)d_in[1];
  const float* W0 = (const float*)d_in[2];
  const float* b0 = (const float*)d_in[3];
  const float* p0 = (const float*)d_in[4];
  const float* W1 = (const float*)d_in[5];
  const float* b1 = (const float*)d_in[6];
  const float* p1 = (const float*)d_in[7];
  const float* W2 = (const float*)d_in[8];
  const float* b2 = (const float*)d_in[9];
  const float* p2 = (const float*)d_in[10];
  const float* Wg = (const float*)d_in[11];
  const float* bg = (const float*)d_in[12];
  float* out = (float*)d_out;

  unsigned char* ws = (unsigned char*)d_ws;
  float* buf0 = (float*)(ws);                              // 64 MB (pooled L0)
  float* buf1 = (float*)(ws + 67108864ull);                // 64 MB (pooled L1)
  unsigned int* eb0 = (unsigned int*)(ws + 134217728ull);  // 4 MB packed edges
  unsigned int* eb1 = (unsigned int*)(ws + 138412032ull);  // 4 MB
  unsigned short* Wsp = (unsigned short*)(ws + 142606336ull); // 96 KB (~136 MB total)

  // layer 0: n=256 -> k=205
  k_wsplit<<<8, 256, 0, stream>>>(W0, Wsp);
  k_layer<<<GCOUNT, 1024, 0, stream>>>(x, ei, nullptr, eb0, buf0, Wsp,
                                       b0, p0, Wg, bg, out, 256, 205, 1, 0);
  // layer 1: n=205 -> k=164
  k_wsplit<<<8, 256, 0, stream>>>(W1, Wsp);
  k_layer<<<GCOUNT, 1024, 0, stream>>>(buf0, nullptr, eb0, eb1, buf1, Wsp,
                                       b1, p1, Wg, bg, out, 205, 164, 0, 1);
  // layer 2: n=164 -> k=132 (pooled output not needed)
  k_wsplit<<<8, 256, 0, stream>>>(W2, Wsp);
  k_layer<<<GCOUNT, 1024, 0, stream>>>(buf1, nullptr, eb1, eb0, nullptr, Wsp,
                                       b2, p2, Wg, bg, out, 164, 132, 0, 1);
}